// Round 13
// baseline (64.677 us; speedup 1.0000x reference)
//
#include <hip/hip_runtime.h>
#include <hip/hip_fp16.h>

// Problem constants (fixed by setup_inputs): B=2, N=96, L=128
#define NANG 96
#define LDIM 128
#define NPIX (LDIM * LDIM)                 // 16384
#define IMG_ELEMS (2 * NANG * LDIM * LDIM) // 3,145,728
#define TPX 8                              // 2x4 pixel tile per block

union H8 { float4 f4; __half2 h2[4]; };

// ---- Pre-pass: f32 [b][n][row][z] -> f16 [n][row][b][z] (R4-proven) -----
// Tap row (both b) = 512 B contiguous; row byte offset = (n*128+row)*512.
__global__ __launch_bounds__(256)
void convert_transpose(const float* __restrict__ in, __half* __restrict__ out) {
    const int i = blockIdx.x * 256 + threadIdx.x;  // one thread per 8 elems
    const int rowid = i >> 4;                      // global input row (b,n,row)
    const int zo = i & 15;
    const int b = rowid / (NANG * LDIM);
    const int rem = rowid - b * (NANG * LDIM);     // n*128 + row

    const float4 a = *(const float4*)(in + (size_t)i * 8);
    const float4 c = *(const float4*)(in + (size_t)i * 8 + 4);
    H8 u;
    u.h2[0] = __float22half2_rn(make_float2(a.x, a.y));
    u.h2[1] = __float22half2_rn(make_float2(a.z, a.w));
    u.h2[2] = __float22half2_rn(make_float2(c.x, c.y));
    u.h2[3] = __float22half2_rn(make_float2(c.z, c.w));
    *(float4*)(out + ((size_t)(rem * 2 + b) * LDIM + zo * 8)) = u.f4;
}

// ---- Barrier-free direct-L1/L2 backprojection, minimal-chain geo --------
// Block = 256 threads; tile = 2(r) x 4(q) = 8 pixels; 32 threads per pixel
// (b = (tid>>4)&1, zo = tid&15 -> 8 halfs per thread). No stage buffer, no
// main-loop barriers. geo entry = (wA half2-bits, byteoffA, byteoffB,
// wB half2-bits): zero unpack VALU, one v_add per tap address.
__global__ __launch_bounds__(256)
void backproj_direct(const __half* __restrict__ imgh,   // [n][row][b][z] f16
                     const float* __restrict__ angles,  // [N]
                     float* __restrict__ out)           // [B, L, L, L] f32
{
    __shared__ float2 strig[NANG];         // 768 B  (s, c)
    __shared__ uint4  geo[TPX][NANG];      // 12288 B
    __shared__ float  snorm[TPX];          // 32 B

    const int tid = threadIdx.x;
    const int rt = blockIdx.x >> 5;    // 0..63
    const int qt = blockIdx.x & 31;    // 0..31
    const int r0 = rt * 2;
    const int q0 = qt * 4;

    // ---- Phase 0: per-angle sincos ----
    if (tid < NANG) {
        float s, c;
        sincosf((270.0f - angles[tid]) * 0.017453292519943295f, &s, &c);
        strig[tid] = make_float2(s, c);
    }
    if (tid < TPX) snorm[tid] = 0.0f;
    __syncthreads();

    // ---- Phase 1: geometry (8 px x 96 angles), 3 entries/thread ----
    for (int e = tid; e < TPX * NANG; e += 256) {
        const int px = e / NANG;           // 0..7
        const int n  = e - px * NANG;
        const float2 m = strig[n];
        const float s = m.x, c = m.y;

        const float xr = (float)(q0 + (px & 3)) - 63.5f;
        const float yr = (float)(r0 + (px >> 2)) - 63.5f;
        const float sx =  c * xr + s * yr + 63.5f;
        const float sy = -s * xr + c * yr + 63.5f;

        const float x0f = floorf(sx), y0f = floorf(sy);
        const float wx = sx - x0f, wy = sy - y0f;
        const int x0 = (int)x0f, y0 = (int)y0f;

        const float vy0 = (y0 >= 0 && y0 < LDIM)         ? 1.0f : 0.0f;
        const float vy1 = (y0 + 1 >= 0 && y0 + 1 < LDIM) ? 1.0f : 0.0f;
        const float vx0 = (x0 >= 0 && x0 < LDIM)         ? 1.0f : 0.0f;
        const float vx1 = (x0 + 1 >= 0 && x0 + 1 < LDIM) ? 1.0f : 0.0f;
        const float ycomb = vy0 * (1.0f - wy) + vy1 * wy;

        const float wA = (1.0f - wx) * ycomb * vx0;
        const float wB = wx * ycomb * vx1;

        const int rowA = min(max(x0, 0), LDIM - 1);        // weight 0 when OOB
        const int rowB = min(max(x0 + 1, 0), LDIM - 1);

        const uint ha = (uint)__half_as_ushort(__float2half(wA));
        const uint hb = (uint)__half_as_ushort(__float2half(wB));
        geo[px][n] = make_uint4(ha * 0x10001u,                 // (wA, wA) half2 bits
                                (uint)(((n << 7) + rowA) << 9),// full tap-A byte offset
                                (uint)(((n << 7) + rowB) << 9),// full tap-B byte offset
                                hb * 0x10001u);                // (wB, wB) half2 bits
        atomicAdd(&snorm[px], wA + wB);   // norm is data-independent
    }
    __syncthreads();

    // ---- Phase 2: barrier-free accumulation over angles ----
    const int px = tid >> 5;            // 0..7
    const int b  = (tid >> 4) & 1;
    const int zo = tid & 15;
    const int laneoff = b * 256 + zo * 16;   // byte offset within 512 B row

    const char* __restrict__ base = (const char*)imgh + laneoff;
    const uint4* __restrict__ gb = &geo[px][0];

    __half2 acc[4] = {};

    #pragma unroll 4
    for (int a = 0; a < NANG; ++a) {
        const uint4 g = gb[a];
        H8 u0, u1;
        u0.f4 = *(const float4*)(base + g.y);
        u1.f4 = *(const float4*)(base + g.z);
        __half2 wa2, wb2;
        wa2 = *(const __half2*)&g.x;
        wb2 = *(const __half2*)&g.w;
        #pragma unroll
        for (int k = 0; k < 4; ++k) {
            acc[k] = __hfma2(wa2, u0.h2[k], acc[k]);
            acc[k] = __hfma2(wb2, u1.h2[k], acc[k]);
        }
    }

    // ---- Epilogue: fp16 acc -> f32, divide by precomputed norm ----
    const int r = r0 + (px >> 2);
    const int q = q0 + (px & 3);
    const float inv = 1.0f / (snorm[px] + 1e-11f);
    const float2 f0 = __half22float2(acc[0]);
    const float2 f1 = __half22float2(acc[1]);
    const float2 f2 = __half22float2(acc[2]);
    const float2 f3 = __half22float2(acc[3]);
    float* op = out + ((((size_t)b * LDIM + r) * LDIM + q) * LDIM + zo * 8);
    *(float4*)op     = make_float4(f0.x * inv, f0.y * inv, f1.x * inv, f1.y * inv);
    *(float4*)(op+4) = make_float4(f2.x * inv, f2.y * inv, f3.x * inv, f3.y * inv);
}

// ---- Fallback f32 kernel (proven in R0) if ws can't hold fp16 image ----
__global__ __launch_bounds__(256)
void backproj_f32(const float* __restrict__ image,
                  const float* __restrict__ angles,
                  float* __restrict__ out)
{
    __shared__ float4 geo[4 * NANG];
    const int tid = threadIdx.x;
    const int p0 = blockIdx.x * 4;

    for (int e = tid; e < 4 * NANG; e += 256) {
        const int sub = e / NANG;
        const int n   = e - sub * NANG;
        const int p   = p0 + sub;
        const int r   = p >> 7;
        const int q   = p & 127;
        float s, c;
        sincosf((270.0f - angles[n]) * 0.017453292519943295f, &s, &c);
        const float xr = (float)q - 63.5f;
        const float yr = (float)r - 63.5f;
        const float sx =  c * xr + s * yr + 63.5f;
        const float sy = -s * xr + c * yr + 63.5f;
        const float x0f = floorf(sx), y0f = floorf(sy);
        const float wx = sx - x0f, wy = sy - y0f;
        const int x0 = (int)x0f, y0 = (int)y0f;
        const float vy0 = (y0 >= 0 && y0 < LDIM) ? 1.0f : 0.0f;
        const float vy1 = (y0 + 1 >= 0 && y0 + 1 < LDIM) ? 1.0f : 0.0f;
        const float vx0 = (x0 >= 0 && x0 < LDIM) ? 1.0f : 0.0f;
        const float vx1 = (x0 + 1 >= 0 && x0 + 1 < LDIM) ? 1.0f : 0.0f;
        const float ycomb = vy0 * (1.0f - wy) + vy1 * wy;
        geo[e] = make_float4((1.0f - wx) * ycomb * vx0, wx * ycomb * vx1,
                             __int_as_float(min(max(x0, 0), LDIM - 1) * LDIM),
                             __int_as_float(min(max(x0 + 1, 0), LDIM - 1) * LDIM));
    }
    __syncthreads();

    const int sub  = tid >> 6;
    const int lane = tid & 63;
    const int b    = lane >> 5;
    const int z    = (lane & 31) * 4;
    const int p    = p0 + sub;
    const int r    = p >> 7;
    const int q    = p & 127;

    const float* imgb = image + (size_t)b * NANG * NPIX + z;
    const float4* __restrict__ gbase = &geo[sub * NANG];
    float4 acc = make_float4(0.f, 0.f, 0.f, 0.f);
    float nacc = 0.f;

    #pragma unroll 4
    for (int n = 0; n < NANG; ++n) {
        const float4 g = gbase[n];
        const float* rowbase = imgb + n * NPIX;
        const float4 v0 = *(const float4*)(rowbase + __float_as_int(g.z));
        const float4 v1 = *(const float4*)(rowbase + __float_as_int(g.w));
        acc.x = fmaf(g.x, v0.x, fmaf(g.y, v1.x, acc.x));
        acc.y = fmaf(g.x, v0.y, fmaf(g.y, v1.y, acc.y));
        acc.z = fmaf(g.x, v0.z, fmaf(g.y, v1.z, acc.z));
        acc.w = fmaf(g.x, v0.w, fmaf(g.y, v1.w, acc.w));
        nacc += g.x + g.y;
    }
    const float inv = 1.0f / (nacc + 1e-11f);
    *(float4*)(out + ((((size_t)b * LDIM + r) * LDIM + q) * LDIM + z)) =
        make_float4(acc.x * inv, acc.y * inv, acc.z * inv, acc.w * inv);
}

extern "C" void kernel_launch(void* const* d_in, const int* in_sizes, int n_in,
                              void* d_out, int out_size, void* d_ws, size_t ws_size,
                              hipStream_t stream) {
    const float* image  = (const float*)d_in[0];   // [2, 96, 128, 128] f32
    const float* angles = (const float*)d_in[1];   // [96] f32
    float* out = (float*)d_out;                    // [2, 128, 128, 128] f32

    const size_t need = (size_t)IMG_ELEMS * sizeof(__half);  // 6.29 MB
    if (ws_size >= need) {
        __half* imgh = (__half*)d_ws;
        convert_transpose<<<IMG_ELEMS / 8 / 256, 256, 0, stream>>>(image, imgh);
        backproj_direct<<<2048, 256, 0, stream>>>(imgh, angles, out);
    } else {
        backproj_f32<<<NPIX / 4, 256, 0, stream>>>(image, angles, out);
    }
}